// Round 3
// baseline (1320.761 us; speedup 1.0000x reference)
//
#include <hip/hip_runtime.h>
#include <hip/hip_bf16.h>

#define B_   16
#define T_   2048
#define E_   1024
#define S_   2000
#define HID_ 150
#define GI_  3072

constexpr int ROWS = 16;          // rows (tokens/spans) per MLP block
constexpr int MLP_THREADS = 192;  // 3 waves; 150 active in HID stages

// MLP: IN_DIM -> HID (relu) -> HID (relu) -> 1, ROWS rows per block. All f32.
template<int IN_DIM>
__global__ __launch_bounds__(MLP_THREADS)
void mlp_kernel(const float* __restrict__ xin,
                const float* __restrict__ W1, const float* __restrict__ b1,
                const float* __restrict__ W2, const float* __restrict__ b2,
                const float* __restrict__ W3, const float* __restrict__ b3,
                float* __restrict__ outp)
{
    __shared__ float xsT[128][ROWS];   // transposed chunk: xsT[e][row]
    __shared__ float h1T[HID_][ROWS];
    __shared__ float h2T[HID_][ROWS];

    const int tid = threadIdx.x;
    const long long row0 = (long long)blockIdx.x * ROWS;

    float acc[ROWS];
#pragma unroll
    for (int t = 0; t < ROWS; ++t) acc[t] = 0.f;

    // ---- stage 1: IN_DIM -> HID, chunked by 128 ----
    for (int ec = 0; ec < IN_DIM / 128; ++ec) {
        for (int i = tid; i < ROWS * 32; i += MLP_THREADS) {  // 32 float4/row
            int t = i >> 5, p = i & 31;
            float4 v = *(const float4*)
                (xin + (row0 + t) * IN_DIM + ec * 128 + p * 4);
            xsT[p * 4 + 0][t] = v.x;
            xsT[p * 4 + 1][t] = v.y;
            xsT[p * 4 + 2][t] = v.z;
            xsT[p * 4 + 3][t] = v.w;
        }
        __syncthreads();
        if (tid < HID_) {
            const float* w = W1 + (long long)(ec * 128) * HID_ + tid;
#pragma unroll 4
            for (int e = 0; e < 128; ++e) {
                float wv = w[(long long)e * HID_];
                const float4* xr = (const float4*)&xsT[e][0];
#pragma unroll
                for (int q = 0; q < 4; ++q) {
                    float4 a = xr[q];
                    acc[q * 4 + 0] += a.x * wv;
                    acc[q * 4 + 1] += a.y * wv;
                    acc[q * 4 + 2] += a.z * wv;
                    acc[q * 4 + 3] += a.w * wv;
                }
            }
        }
        __syncthreads();
    }
    if (tid < HID_) {
        float bb = b1[tid];
#pragma unroll
        for (int t = 0; t < ROWS; ++t) {
            float h = acc[t] + bb;
            h1T[tid][t] = h > 0.f ? h : 0.f;
        }
    }
    __syncthreads();

    // ---- stage 2: HID -> HID ----
    float acc2[ROWS];
#pragma unroll
    for (int t = 0; t < ROWS; ++t) acc2[t] = 0.f;
    if (tid < HID_) {
        const float* w = W2 + tid;
        for (int k = 0; k < HID_; ++k) {
            float wv = w[(long long)k * HID_];
            const float4* hr = (const float4*)&h1T[k][0];
#pragma unroll
            for (int q = 0; q < 4; ++q) {
                float4 a = hr[q];
                acc2[q * 4 + 0] += a.x * wv;
                acc2[q * 4 + 1] += a.y * wv;
                acc2[q * 4 + 2] += a.z * wv;
                acc2[q * 4 + 3] += a.w * wv;
            }
        }
        float bb = b2[tid];
#pragma unroll
        for (int t = 0; t < ROWS; ++t) {
            float h = acc2[t] + bb;
            h2T[tid][t] = h > 0.f ? h : 0.f;
        }
    }
    __syncthreads();

    // ---- stage 3: HID -> 1 ----
    if (tid < ROWS) {
        float s = b3[0];
        for (int k = 0; k < HID_; ++k) s += h2T[k][tid] * W3[k];
        outp[row0 + tid] = s;
    }
}

// span_emb = [x[start], x[end], sum_{t=start..end} x[t]*attn[t]]  (f32 out)
__global__ __launch_bounds__(256)
void span_kernel(const float* __restrict__ x, const float* __restrict__ attn,
                 const int* __restrict__ starts, const int* __restrict__ lengths,
                 const int* __restrict__ nspans, float* __restrict__ out)
{
    const int blk = blockIdx.x;        // b*S + s
    const int b = blk / S_;
    const int s = blk - b * S_;
    const int tid = threadIdx.x;       // each thread: 4 consecutive elements
    float* orow = out + (long long)blk * (3 * E_);

    if (s >= nspans[b]) {
        float4 z = make_float4(0.f, 0.f, 0.f, 0.f);
        *(float4*)(orow + tid * 4)          = z;
        *(float4*)(orow + E_ + tid * 4)     = z;
        *(float4*)(orow + 2 * E_ + tid * 4) = z;
        return;
    }
    const int st = starts[blk];
    const int en = st + lengths[blk];   // inclusive end index, < T
    const float* xb = x + (long long)b * T_ * E_;

    float4 vs = *(const float4*)(xb + (long long)st * E_ + tid * 4);
    float4 ve = *(const float4*)(xb + (long long)en * E_ + tid * 4);
    *(float4*)(orow + tid * 4)      = vs;   // raw copy: bit-exact g_start
    *(float4*)(orow + E_ + tid * 4) = ve;   // bit-exact g_end

    float4 a4 = make_float4(0.f, 0.f, 0.f, 0.f);
    const float* ab = attn + b * T_;
    for (int t = st; t <= en; ++t) {
        float a = ab[t];
        float4 v = *(const float4*)(xb + (long long)t * E_ + tid * 4);
        a4.x += v.x * a; a4.y += v.y * a; a4.z += v.z * a; a4.w += v.w * a;
    }
    *(float4*)(orow + 2 * E_ + tid * 4) = a4;
}

extern "C" void kernel_launch(void* const* d_in, const int* in_sizes, int n_in,
                              void* d_out, int out_size, void* d_ws, size_t ws_size,
                              hipStream_t stream) {
    const float* x       = (const float*)d_in[0];
    const int*   starts  = (const int*)d_in[1];
    const int*   lengths = (const int*)d_in[2];
    const int*   nspans  = (const int*)d_in[3];
    const float* Wa1 = (const float*)d_in[4];
    const float* ba1 = (const float*)d_in[5];
    const float* Wa2 = (const float*)d_in[6];
    const float* ba2 = (const float*)d_in[7];
    const float* Wa3 = (const float*)d_in[8];
    const float* ba3 = (const float*)d_in[9];
    const float* Ws1 = (const float*)d_in[10];
    const float* bs1 = (const float*)d_in[11];
    const float* Ws2 = (const float*)d_in[12];
    const float* bs2 = (const float*)d_in[13];
    const float* Ws3 = (const float*)d_in[14];
    const float* bs3 = (const float*)d_in[15];

    float* out        = (float*)d_out;                       // span_emb [B,S,3E]
    float* out_scores = out + (long long)B_ * S_ * 3 * E_;   // scores [B,S,1]
    float* attn       = (float*)d_ws;                        // B*T floats = 128 KiB

    // 1) attention score per token
    mlp_kernel<E_>
        <<<(B_ * T_) / ROWS, MLP_THREADS, 0, stream>>>
        (x, Wa1, ba1, Wa2, ba2, Wa3, ba3, attn);

    // 2) span embeddings (direct ragged sum; lengths < 24)
    span_kernel<<<B_ * S_, 256, 0, stream>>>(x, attn, starts, lengths, nspans, out);

    // 3) mention scores from span_emb (read back as f32)
    mlp_kernel<GI_>
        <<<(B_ * S_) / ROWS, MLP_THREADS, 0, stream>>>
        (out, Ws1, bs1, Ws2, bs2, Ws3, bs3, out_scores);
}

// Round 4
// 536.175 us; speedup vs baseline: 2.4633x; 2.4633x over previous
//
#include <hip/hip_runtime.h>
#include <hip/hip_bf16.h>

#define B_   16
#define T_   2048
#define E_   1024
#define S_   2000
#define HID_ 150
#define GI_  3072

typedef __attribute__((ext_vector_type(8))) short short8;   // 8 bf16 (4 VGPRs)
typedef __attribute__((ext_vector_type(4))) float f32x4;

constexpr int NPAD = 160;        // HID padded to 10 MFMA col-tiles
constexpr int LSTR = 168;        // LDS row stride (bf16 elems): 336 B, 16B-aligned, 2-way banks

__device__ inline short8 pack8(float4 a, float4 b) {
    union { __hip_bfloat162 h[4]; short8 s; } u;
    u.h[0] = __float22bfloat162_rn(make_float2(a.x, a.y));
    u.h[1] = __float22bfloat162_rn(make_float2(a.z, a.w));
    u.h[2] = __float22bfloat162_rn(make_float2(b.x, b.y));
    u.h[3] = __float22bfloat162_rn(make_float2(b.z, b.w));
    return u.s;
}

// W [K x 150] f32  ->  Wt [160][DSTK] bf16, zero-padded (n>=150 or k>=SRCK)
template<int SRCK, int DSTK>
__global__ __launch_bounds__(256)
void transpose_w(const float* __restrict__ src, __hip_bfloat16* __restrict__ dst) {
    int i = blockIdx.x * 256 + threadIdx.x;      // i = n*DSTK + k
    if (i >= NPAD * DSTK) return;
    int n = i / DSTK, k = i - n * DSTK;
    float v = (n < HID_ && k < SRCK) ? src[(long long)k * HID_ + n] : 0.f;
    dst[i] = __float2bfloat16(v);
}

// Full MLP: K1 -> 150 (relu) -> 150 (relu) -> 1, 128 rows per block, MFMA bf16.
// Wt1 [NPAD][K1] bf16 (pre-transposed), Wt2 [NPAD][NPAD] bf16 (zero-padded).
template<int K1>
__global__ __launch_bounds__(256)
void mlp_mfma(const float* __restrict__ xin,
              const __hip_bfloat16* __restrict__ Wt1, const float* __restrict__ b1,
              const __hip_bfloat16* __restrict__ Wt2, const float* __restrict__ b2,
              const float* __restrict__ W3, const float* __restrict__ b3,
              float* __restrict__ outp)
{
    __shared__ __hip_bfloat16 hl[128 * LSTR];

    const int tid  = threadIdx.x;
    const int lane = tid & 63;
    const int w    = tid >> 6;          // wave 0..3
    const int rg   = w >> 1;            // row group (64 rows each)
    const int cg   = w & 1;             // col group (80 cols each)
    const int lr   = lane & 15;         // fragment row/col index
    const int lk   = (lane >> 4) * 8;   // fragment k offset (8 contiguous)

    const long long row0 = (long long)blockIdx.x * 128;

    // ---------------- stage 1: K1 -> 160 (MFMA) ----------------
    f32x4 acc[4][5];
#pragma unroll
    for (int rt = 0; rt < 4; ++rt)
#pragma unroll
        for (int nt = 0; nt < 5; ++nt) acc[rt][nt] = (f32x4){0.f, 0.f, 0.f, 0.f};

    const float* xrow[4];
#pragma unroll
    for (int rt = 0; rt < 4; ++rt)
        xrow[rt] = xin + (row0 + rg * 64 + rt * 16 + lr) * K1;
    const __hip_bfloat16* brow[5];
#pragma unroll
    for (int nt = 0; nt < 5; ++nt)
        brow[nt] = Wt1 + (long long)(cg * 80 + nt * 16 + lr) * K1;

    for (int ks = 0; ks < K1 / 32; ++ks) {
        const int k0 = ks * 32 + lk;
        short8 bfr[5];
#pragma unroll
        for (int nt = 0; nt < 5; ++nt)
            bfr[nt] = *(const short8*)(brow[nt] + k0);
        short8 afr[4];
#pragma unroll
        for (int rt = 0; rt < 4; ++rt) {
            float4 a = *(const float4*)(xrow[rt] + k0);
            float4 b = *(const float4*)(xrow[rt] + k0 + 4);
            afr[rt] = pack8(a, b);
        }
#pragma unroll
        for (int rt = 0; rt < 4; ++rt)
#pragma unroll
            for (int nt = 0; nt < 5; ++nt)
                acc[rt][nt] = __builtin_amdgcn_mfma_f32_16x16x32_bf16(
                    afr[rt], bfr[nt], acc[rt][nt], 0, 0, 0);
    }

    // bias + relu -> hl (bf16)
#pragma unroll
    for (int nt = 0; nt < 5; ++nt) {
        const int ch = cg * 80 + nt * 16 + lr;
        const float bb = (ch < HID_) ? b1[ch] : 0.f;
#pragma unroll
        for (int rt = 0; rt < 4; ++rt)
#pragma unroll
            for (int r = 0; r < 4; ++r) {
                const int row = rg * 64 + rt * 16 + (lane >> 4) * 4 + r;
                float h = acc[rt][nt][r] + bb;
                hl[row * LSTR + ch] = __float2bfloat16(h > 0.f ? h : 0.f);
            }
    }
    __syncthreads();

    // ---------------- stage 2: 160 -> 160 (MFMA, K=160) ----------------
    f32x4 acc2[4][5];
#pragma unroll
    for (int rt = 0; rt < 4; ++rt)
#pragma unroll
        for (int nt = 0; nt < 5; ++nt) acc2[rt][nt] = (f32x4){0.f, 0.f, 0.f, 0.f};

#pragma unroll
    for (int ks = 0; ks < 5; ++ks) {
        const int k0 = ks * 32 + lk;
        short8 bfr[5];
#pragma unroll
        for (int nt = 0; nt < 5; ++nt)
            bfr[nt] = *(const short8*)(Wt2 + (cg * 80 + nt * 16 + lr) * NPAD + k0);
        short8 afr[4];
#pragma unroll
        for (int rt = 0; rt < 4; ++rt)
            afr[rt] = *(const short8*)(&hl[(rg * 64 + rt * 16 + lr) * LSTR + k0]);
#pragma unroll
        for (int rt = 0; rt < 4; ++rt)
#pragma unroll
            for (int nt = 0; nt < 5; ++nt)
                acc2[rt][nt] = __builtin_amdgcn_mfma_f32_16x16x32_bf16(
                    afr[rt], bfr[nt], acc2[rt][nt], 0, 0, 0);
    }
    __syncthreads();   // all stage-2 reads of hl done before overwrite

    // bias + relu -> hl (h2)
#pragma unroll
    for (int nt = 0; nt < 5; ++nt) {
        const int ch = cg * 80 + nt * 16 + lr;
        const float bb = (ch < HID_) ? b2[ch] : 0.f;
#pragma unroll
        for (int rt = 0; rt < 4; ++rt)
#pragma unroll
            for (int r = 0; r < 4; ++r) {
                const int row = rg * 64 + rt * 16 + (lane >> 4) * 4 + r;
                float h = acc2[rt][nt][r] + bb;
                hl[row * LSTR + ch] = __float2bfloat16(h > 0.f ? h : 0.f);
            }
    }
    __syncthreads();

    // ---------------- stage 3: 150 -> 1 ----------------
    {
        const int row = tid >> 1, half = tid & 1;
        float s = 0.f;
        const int kb = half * 75;
        for (int k = 0; k < 75; ++k)
            s += __bfloat162float(hl[row * LSTR + kb + k]) * W3[kb + k];
        s += __shfl_xor(s, 1);
        if (half == 0) outp[row0 + row] = s + b3[0];
    }
}

// span_emb = [x[start], x[end], sum_{t=start..end} x[t]*attn[t]]  (f32 out)
__global__ __launch_bounds__(256)
void span_kernel(const float* __restrict__ x, const float* __restrict__ attn,
                 const int* __restrict__ starts, const int* __restrict__ lengths,
                 const int* __restrict__ nspans, float* __restrict__ out)
{
    const int blk = blockIdx.x;        // b*S + s
    const int b = blk / S_;
    const int s = blk - b * S_;
    const int tid = threadIdx.x;       // each thread: 4 consecutive elements
    float* orow = out + (long long)blk * (3 * E_);

    if (s >= nspans[b]) {
        float4 z = make_float4(0.f, 0.f, 0.f, 0.f);
        *(float4*)(orow + tid * 4)          = z;
        *(float4*)(orow + E_ + tid * 4)     = z;
        *(float4*)(orow + 2 * E_ + tid * 4) = z;
        return;
    }
    const int st = starts[blk];
    const int en = st + lengths[blk];   // inclusive end index, < T
    const float* xb = x + (long long)b * T_ * E_;

    float4 vs = *(const float4*)(xb + (long long)st * E_ + tid * 4);
    float4 ve = *(const float4*)(xb + (long long)en * E_ + tid * 4);
    *(float4*)(orow + tid * 4)      = vs;   // bit-exact g_start
    *(float4*)(orow + E_ + tid * 4) = ve;   // bit-exact g_end

    float4 a4 = make_float4(0.f, 0.f, 0.f, 0.f);
    const float* ab = attn + b * T_;
    for (int t = st; t <= en; ++t) {
        float a = ab[t];
        float4 v = *(const float4*)(xb + (long long)t * E_ + tid * 4);
        a4.x += v.x * a; a4.y += v.y * a; a4.z += v.z * a; a4.w += v.w * a;
    }
    *(float4*)(orow + 2 * E_ + tid * 4) = a4;
}

extern "C" void kernel_launch(void* const* d_in, const int* in_sizes, int n_in,
                              void* d_out, int out_size, void* d_ws, size_t ws_size,
                              hipStream_t stream) {
    const float* x       = (const float*)d_in[0];
    const int*   starts  = (const int*)d_in[1];
    const int*   lengths = (const int*)d_in[2];
    const int*   nspans  = (const int*)d_in[3];
    const float* Wa1 = (const float*)d_in[4];
    const float* ba1 = (const float*)d_in[5];
    const float* Wa2 = (const float*)d_in[6];
    const float* ba2 = (const float*)d_in[7];
    const float* Wa3 = (const float*)d_in[8];
    const float* ba3 = (const float*)d_in[9];
    const float* Ws1 = (const float*)d_in[10];
    const float* bs1 = (const float*)d_in[11];
    const float* Ws2 = (const float*)d_in[12];
    const float* bs2 = (const float*)d_in[13];
    const float* Ws3 = (const float*)d_in[14];
    const float* bs3 = (const float*)d_in[15];

    float* out        = (float*)d_out;                       // span_emb [B,S,3E]
    float* out_scores = out + (long long)B_ * S_ * 3 * E_;   // scores [B,S]

    // workspace layout (16B-aligned offsets)
    char* ws = (char*)d_ws;
    float*          attn = (float*)ws;                         // 131072 B
    __hip_bfloat16* Wt1a = (__hip_bfloat16*)(ws + 131072);     // 160*1024*2
    __hip_bfloat16* Wt2a = (__hip_bfloat16*)(ws + 458752);     // 160*160*2
    __hip_bfloat16* Wt1s = (__hip_bfloat16*)(ws + 509952);     // 160*3072*2
    __hip_bfloat16* Wt2s = (__hip_bfloat16*)(ws + 1492992);    // 160*160*2

    // 0) pre-transpose weights to bf16 [NPAD][K]
    transpose_w<E_,  E_ ><<<(NPAD * E_ ) / 256, 256, 0, stream>>>(Wa1, Wt1a);
    transpose_w<HID_,NPAD><<<(NPAD * NPAD) / 256, 256, 0, stream>>>(Wa2, Wt2a);
    transpose_w<GI_, GI_ ><<<(NPAD * GI_ ) / 256, 256, 0, stream>>>(Ws1, Wt1s);
    transpose_w<HID_,NPAD><<<(NPAD * NPAD) / 256, 256, 0, stream>>>(Ws2, Wt2s);

    // 1) attention score per token (32768 rows)
    mlp_mfma<E_><<<(B_ * T_) / 128, 256, 0, stream>>>
        (x, Wt1a, ba1, Wt2a, ba2, Wa3, ba3, attn);

    // 2) span embeddings (direct ragged sum; lengths < 24)
    span_kernel<<<B_ * S_, 256, 0, stream>>>(x, attn, starts, lengths, nspans, out);

    // 3) mention scores from span_emb (32000 rows)
    mlp_mfma<GI_><<<(B_ * S_) / 128, 256, 0, stream>>>
        (out, Wt1s, bs1, Wt2s, bs2, Ws3, bs3, out_scores);
}